// Round 5
// baseline (112.878 us; speedup 1.0000x reference)
//
#include <hip/hip_runtime.h>

typedef __attribute__((ext_vector_type(8))) short bf8;
typedef __attribute__((ext_vector_type(4))) float f4;

static __device__ __forceinline__ short bfr(float x) {
    union { float f; unsigned u; } v; v.f = x;
    return (short)((v.u + 0x7FFF + ((v.u >> 16) & 1)) >> 16);  // RNE
}
static __device__ __forceinline__ float bf2f(short s) {
    union { float f; unsigned u; } v; v.u = ((unsigned)(unsigned short)s) << 16;
    return v.f;
}
static __device__ __forceinline__ bf8 pack8(float4 a, float4 b) {
    bf8 r;
    r[0] = bfr(a.x); r[1] = bfr(a.y); r[2] = bfr(a.z); r[3] = bfr(a.w);
    r[4] = bfr(b.x); r[5] = bfr(b.y); r[6] = bfr(b.z); r[7] = bfr(b.w);
    return r;
}

// Single fully-fused kernel. Grid 256 x 1024 thr (1 block/CU, 16 waves =
// 4 waves/SIMD; R4's 8-wave version ran 2/SIMD and was latency-exposed at
// 53 us with all pipes <15%). Block = (b = blk>>6, 8-row q-tile i0).
// Uses qk = (q @ Wk) @ keys^T + (q . bk) so k-proj is never materialized.
//   prefetch: relations + Wk column-gather B-frags (independent of A/B output;
//             their latency hides under phase A).
//   A: q = queries_rows @ Wq^T + bq     (8 MFMA/wave, cols w*16..w*16+15)
//   B: t = q @ Wk  (8 reg-only MFMA)    + qbk[i] = dot(q[i], bk)
//   C: qk = t @ keys^T (fp32 keys packed on the fly, 32 j-cols/wave),
//      qr = q @ rel_emb^T, 3-barrier softmax (best measured structure).
// A-rows duplicated (n15&7) so the 16x16 MFMA tile carries 8 real rows.
// Do NOT shrink the 8-row i-tile (R2: doubled K L2 traffic, 18->52 us).
__global__ __launch_bounds__(1024, 4) void fused_attn(
    const float* __restrict__ queries, const float* __restrict__ keys,
    const int* __restrict__ relations, const float* __restrict__ Wq,
    const float* __restrict__ bq, const float* __restrict__ Wk,
    const float* __restrict__ bk, const float* __restrict__ rel_emb,
    float* __restrict__ out)
{
    __shared__ short q_l[8][264];   // q rows bf16 (stride 264: 16B-aligned rows)
    __shared__ short t_l[8][264];   // t rows bf16
    __shared__ float qr_l[16][112];
    __shared__ float red_m[16][16];
    __shared__ float red_s[16][16];
    __shared__ float qbk_l[8];

    int blk = blockIdx.x;
    int b = blk >> 6;
    int i0 = (blk & 63) * 8;
    int gi0 = b * 512 + i0;
    int w = threadIdx.x >> 6;        // 16 waves
    int lane = threadIdx.x & 63;
    int n15 = lane & 15, quad = lane >> 4;
    int j0 = w * 32;

    // ---- prefetch 1: relations (HBM ~900cy, hides under phases A/B) ----
    // C row m=quad*4+reg -> real row (quad&1)*4+reg
    const int* rb = relations + (gi0 + (quad & 1) * 4) * 512 + j0 + n15;
    int rv[2][4];
#pragma unroll
    for (int reg = 0; reg < 4; reg++)
#pragma unroll
        for (int nt = 0; nt < 2; nt++)
            rv[nt][reg] = rb[reg * 512 + nt * 16];

    // ---- prefetch 2: Wk column-gather B-frags for phase B (depend only on
    // Wk; latency hides under phase A). Col h = w*16+n15; 64B-coalesced per
    // 16-lane group, L2-resident (Wk = 256 KB). ----
    int h = w * 16 + n15;
    bf8 wkfr[8];
#pragma unroll
    for (int kk = 0; kk < 8; kk++) {
        const float* wp = Wk + (kk * 32 + quad * 8) * 256 + h;
        float t0[8];
#pragma unroll
        for (int j = 0; j < 8; j++) t0[j] = wp[j * 256];
#pragma unroll
        for (int j = 0; j < 8; j++) wkfr[kk][j] = bfr(t0[j]);
    }

    f4 z = {0.f, 0.f, 0.f, 0.f};

    // ---- Phase A: q-proj. Wave w -> cols w*16..w*16+15 ----
    int arow = gi0 + (n15 & 7);      // rows 8..15 duplicate 0..7
    bf8 aq[8];
#pragma unroll
    for (int kk = 0; kk < 8; kk++) {
        const float4* ap = (const float4*)(queries + arow * 256 + kk * 32 + quad * 8);
        aq[kk] = pack8(ap[0], ap[1]);
    }
    {
        f4 cq = z;
        int colA = w * 16 + n15;
        const float* wqr = Wq + colA * 256 + quad * 8;
#pragma unroll
        for (int kk = 0; kk < 8; kk++) {
            const float4* bp = (const float4*)(wqr + kk * 32);
            cq = __builtin_amdgcn_mfma_f32_16x16x32_bf16(aq[kk], pack8(bp[0], bp[1]),
                                                         cq, 0, 0, 0);
        }
        if (quad < 2) {
            float bv = bq[colA];
#pragma unroll
            for (int reg = 0; reg < 4; reg++)
                q_l[quad * 4 + reg][colA] = bfr(cq[reg] + bv);
        }
    }
    __syncthreads();

    // ---- Phase B: t = q @ Wk (reg-only MFMAs, B-frags prefetched) ----
    bf8 aQ[8];  // q as A-frag (also reused for qr in phase C)
#pragma unroll
    for (int kk = 0; kk < 8; kk++)
        aQ[kk] = *(const bf8*)&q_l[n15 & 7][kk * 32 + quad * 8];

    {
        f4 ct = z;
#pragma unroll
        for (int kk = 0; kk < 8; kk++)
            ct = __builtin_amdgcn_mfma_f32_16x16x32_bf16(aQ[kk], wkfr[kk], ct, 0, 0, 0);
        if (quad < 2) {
#pragma unroll
            for (int reg = 0; reg < 4; reg++)
                t_l[quad * 4 + reg][h] = bfr(ct[reg]);
        }
    }

    // qbk[i] = dot(q[i], bk): wave w (<8) handles row w (4 elems/lane)
    if (w < 8) {
        const short* qp = &q_l[w][lane * 4];
        float4 bkv = *(const float4*)(bk + lane * 4);
        float a0 = bf2f(qp[0]) * bkv.x + bf2f(qp[1]) * bkv.y +
                   bf2f(qp[2]) * bkv.z + bf2f(qp[3]) * bkv.w;
#pragma unroll
        for (int d = 1; d <= 32; d <<= 1) a0 += __shfl_xor(a0, d, 64);
        if (lane == 0) qbk_l[w] = a0;
    }
    __syncthreads();

    // ---- Phase C: qk = t @ keys^T, qr = q @ rel_emb^T, softmax ----
    bf8 aT[8];
#pragma unroll
    for (int kk = 0; kk < 8; kk++)
        aT[kk] = *(const bf8*)&t_l[n15 & 7][kk * 32 + quad * 8];

    f4 c[2] = {z, z};
#pragma unroll
    for (int nt = 0; nt < 2; nt++) {
        int krow = b * 512 + j0 + nt * 16 + n15;
        const float* kr = keys + krow * 256 + quad * 8;
#pragma unroll
        for (int kk = 0; kk < 8; kk++) {
            const float4* kp = (const float4*)(kr + kk * 32);
            c[nt] = __builtin_amdgcn_mfma_f32_16x16x32_bf16(aT[kk], pack8(kp[0], kp[1]),
                                                            c[nt], 0, 0, 0);
        }
    }

    if (w < 7) {  // qr: rel rows w*16..w*16+15, rows >= 99 are zero
        f4 cr = z;
        int rrow = w * 16 + n15;
        bool valid = rrow < 99;
        const float* rp = rel_emb + (valid ? rrow : 0) * 256 + quad * 8;
#pragma unroll
        for (int kk = 0; kk < 8; kk++) {
            const float4* rpp = (const float4*)(rp + kk * 32);
            float4 x0 = rpp[0], x1 = rpp[1];
            if (!valid) { x0 = make_float4(0.f, 0.f, 0.f, 0.f); x1 = x0; }
            cr = __builtin_amdgcn_mfma_f32_16x16x32_bf16(aQ[kk], pack8(x0, x1), cr, 0, 0, 0);
        }
#pragma unroll
        for (int reg = 0; reg < 4; reg++)
            qr_l[quad * 4 + reg][rrow] = cr[reg];  // dup rows get dup values
    }
    __syncthreads();

    const float scale = 0.0625f;  // 1/sqrt(256)
    float lg[2][4];
#pragma unroll
    for (int nt = 0; nt < 2; nt++)
#pragma unroll
        for (int reg = 0; reg < 4; reg++)
            lg[nt][reg] = (c[nt][reg] + qr_l[quad * 4 + reg][rv[nt][reg]] +
                           qbk_l[(quad & 1) * 4 + reg]) * scale;

    float pm[4];
#pragma unroll
    for (int reg = 0; reg < 4; reg++) {
        float m = fmaxf(lg[0][reg], lg[1][reg]);
#pragma unroll
        for (int d = 1; d <= 8; d <<= 1) m = fmaxf(m, __shfl_xor(m, d, 64));
        pm[reg] = m;
    }
    if (n15 == 0)
#pragma unroll
        for (int reg = 0; reg < 4; reg++) red_m[quad * 4 + reg][w] = pm[reg];
    __syncthreads();
    float M[4];
#pragma unroll
    for (int reg = 0; reg < 4; reg++) {
        f4 a0 = *(const f4*)&red_m[quad * 4 + reg][0];
        f4 a1 = *(const f4*)&red_m[quad * 4 + reg][4];
        f4 a2 = *(const f4*)&red_m[quad * 4 + reg][8];
        f4 a3 = *(const f4*)&red_m[quad * 4 + reg][12];
        float m0 = fmaxf(fmaxf(a0[0], a0[1]), fmaxf(a0[2], a0[3]));
        float m1 = fmaxf(fmaxf(a1[0], a1[1]), fmaxf(a1[2], a1[3]));
        float m2 = fmaxf(fmaxf(a2[0], a2[1]), fmaxf(a2[2], a2[3]));
        float m3 = fmaxf(fmaxf(a3[0], a3[1]), fmaxf(a3[2], a3[3]));
        M[reg] = fmaxf(fmaxf(m0, m1), fmaxf(m2, m3));
    }

    float ps[4];
#pragma unroll
    for (int reg = 0; reg < 4; reg++) {
        float s = 0.f;
#pragma unroll
        for (int nt = 0; nt < 2; nt++) {
            float e = __expf(lg[nt][reg] - M[reg]);
            lg[nt][reg] = e;
            s += e;
        }
#pragma unroll
        for (int d = 1; d <= 8; d <<= 1) s += __shfl_xor(s, d, 64);
        ps[reg] = s;
    }
    if (n15 == 0)
#pragma unroll
        for (int reg = 0; reg < 4; reg++) red_s[quad * 4 + reg][w] = ps[reg];
    __syncthreads();
    float inv[4];
#pragma unroll
    for (int reg = 0; reg < 4; reg++) {
        f4 a0 = *(const f4*)&red_s[quad * 4 + reg][0];
        f4 a1 = *(const f4*)&red_s[quad * 4 + reg][4];
        f4 a2 = *(const f4*)&red_s[quad * 4 + reg][8];
        f4 a3 = *(const f4*)&red_s[quad * 4 + reg][12];
        inv[reg] = 1.f / (a0[0] + a0[1] + a0[2] + a0[3] + a1[0] + a1[1] + a1[2] + a1[3] +
                          a2[0] + a2[1] + a2[2] + a2[3] + a3[0] + a3[1] + a3[2] + a3[3]);
    }

    if (quad < 2) {  // rows 0..7 real; quads 2,3 are duplicates
        float* ob = out + (gi0 + quad * 4) * 512 + j0 + n15;
#pragma unroll
        for (int reg = 0; reg < 4; reg++)
#pragma unroll
            for (int nt = 0; nt < 2; nt++)
                ob[reg * 512 + nt * 16] = lg[nt][reg] * inv[reg];
    }
}

extern "C" void kernel_launch(void* const* d_in, const int* in_sizes, int n_in,
                              void* d_out, int out_size, void* d_ws, size_t ws_size,
                              hipStream_t stream) {
    const float* queries = (const float*)d_in[0];
    const float* keys = (const float*)d_in[1];
    const int* relations = (const int*)d_in[2];
    const float* Wq = (const float*)d_in[3];
    const float* bq = (const float*)d_in[4];
    const float* Wk = (const float*)d_in[5];
    const float* bk = (const float*)d_in[6];
    const float* rel_emb = (const float*)d_in[7];
    float* out = (float*)d_out;

    hipLaunchKernelGGL(fused_attn, dim3(256), dim3(1024), 0, stream,
                       queries, keys, relations, Wq, bq, Wk, bk, rel_emb, out);
}

// Round 6
// 111.358 us; speedup vs baseline: 1.0137x; 1.0137x over previous
//
#include <hip/hip_runtime.h>

typedef __attribute__((ext_vector_type(8))) short bf8;
typedef __attribute__((ext_vector_type(4))) float f4;

static __device__ __forceinline__ short bfr(float x) {
    union { float f; unsigned u; } v; v.f = x;
    return (short)((v.u + 0x7FFF + ((v.u >> 16) & 1)) >> 16);  // RNE
}
static __device__ __forceinline__ float bf2f(short s) {
    union { float f; unsigned u; } v; v.u = ((unsigned)(unsigned short)s) << 16;
    return v.f;
}
static __device__ __forceinline__ bf8 pack8(float4 a, float4 b) {
    bf8 r;
    r[0] = bfr(a.x); r[1] = bfr(a.y); r[2] = bfr(a.z); r[3] = bfr(a.w);
    r[4] = bfr(b.x); r[5] = bfr(b.y); r[6] = bfr(b.z); r[7] = bfr(b.w);
    return r;
}

// Single fully-fused kernel. Grid 256 x 1024 thr (1 block/CU, 16 waves =
// 4 waves/SIMD). Block = (b = blk>>6, 8-row q-tile i0).
// qk = (q @ Wk) @ keys^T + (q . bk) so k-proj is never materialized.
// R6 schedule (vs R5: one fewer barrier, keys prefetched pre-barrier):
//   prefetch: relations + Wk column-gather B-frags
//   A: q = queries @ Wq^T + bq          (8 MFMA/wave)        [barrier]
//   B: t = q @ Wk (8 reg-only MFMA); qr = q @ rel_emb^T (w<7, rel_emb loads
//      hide under t MFMAs); qbk dot; THEN issue keys nt=0 prefetch (wkfr regs
//      dead -> fits 128-VGPR cap)                            [barrier]
//   C: qk = t @ keys^T (nt=0 packs from prefetched regs; nt=1 loads inline),
//      3-barrier... now 2-barrier softmax tail.
// A-rows duplicated (n15&7): 16x16 MFMA tile carries 8 real rows. Do NOT
// shrink the 8-row i-tile (R2: 4-row tile = 4x MFMA redundancy, 18->52 us).
__global__ __launch_bounds__(1024, 4) void fused_attn(
    const float* __restrict__ queries, const float* __restrict__ keys,
    const int* __restrict__ relations, const float* __restrict__ Wq,
    const float* __restrict__ bq, const float* __restrict__ Wk,
    const float* __restrict__ bk, const float* __restrict__ rel_emb,
    float* __restrict__ out)
{
    __shared__ short q_l[8][264];   // q rows bf16 (stride 264: 16B-aligned rows)
    __shared__ short t_l[8][264];   // t rows bf16
    __shared__ float qr_l[16][112];
    __shared__ float red_m[16][16];
    __shared__ float red_s[16][16];
    __shared__ float qbk_l[8];

    int blk = blockIdx.x;
    int b = blk >> 6;
    int i0 = (blk & 63) * 8;
    int gi0 = b * 512 + i0;
    int w = threadIdx.x >> 6;        // 16 waves
    int lane = threadIdx.x & 63;
    int n15 = lane & 15, quad = lane >> 4;
    int j0 = w * 32;

    // ---- prefetch 1: relations (HBM ~900cy, hides under phase A) ----
    // C row m=quad*4+reg -> real row (quad&1)*4+reg
    const int* rb = relations + (gi0 + (quad & 1) * 4) * 512 + j0 + n15;
    int rv[2][4];
#pragma unroll
    for (int reg = 0; reg < 4; reg++)
#pragma unroll
        for (int nt = 0; nt < 2; nt++)
            rv[nt][reg] = rb[reg * 512 + nt * 16];

    // ---- prefetch 2: Wk column-gather B-frags for phase B. Col h = w*16+n15;
    // 64B-coalesced per 16-lane group, L2-resident (Wk = 256 KB). ----
    int h = w * 16 + n15;
    bf8 wkfr[8];
#pragma unroll
    for (int kk = 0; kk < 8; kk++) {
        const float* wp = Wk + (kk * 32 + quad * 8) * 256 + h;
        float t0[8];
#pragma unroll
        for (int j = 0; j < 8; j++) t0[j] = wp[j * 256];
#pragma unroll
        for (int j = 0; j < 8; j++) wkfr[kk][j] = bfr(t0[j]);
    }

    f4 z = {0.f, 0.f, 0.f, 0.f};

    // ---- Phase A: q-proj. Wave w -> col w*16+n15 ----
    int arow = gi0 + (n15 & 7);      // rows 8..15 duplicate 0..7
    {
        bf8 aq[8];
#pragma unroll
        for (int kk = 0; kk < 8; kk++) {
            const float4* ap = (const float4*)(queries + arow * 256 + kk * 32 + quad * 8);
            aq[kk] = pack8(ap[0], ap[1]);
        }
        f4 cq = z;
        int colA = w * 16 + n15;
        const float* wqr = Wq + colA * 256 + quad * 8;
#pragma unroll
        for (int kk = 0; kk < 8; kk++) {
            const float4* bp = (const float4*)(wqr + kk * 32);
            cq = __builtin_amdgcn_mfma_f32_16x16x32_bf16(aq[kk], pack8(bp[0], bp[1]),
                                                         cq, 0, 0, 0);
        }
        if (quad < 2) {
            float bv = bq[colA];
#pragma unroll
            for (int reg = 0; reg < 4; reg++)
                q_l[quad * 4 + reg][colA] = bfr(cq[reg] + bv);
        }
    }
    __syncthreads();

    // ---- Phase B: t = q @ Wk (reg-only MFMAs) + qr + qbk ----
    bf8 aQ[8];
#pragma unroll
    for (int kk = 0; kk < 8; kk++)
        aQ[kk] = *(const bf8*)&q_l[n15 & 7][kk * 32 + quad * 8];

    {
        f4 ct = z;
#pragma unroll
        for (int kk = 0; kk < 8; kk++)
            ct = __builtin_amdgcn_mfma_f32_16x16x32_bf16(aQ[kk], wkfr[kk], ct, 0, 0, 0);
        if (quad < 2) {
#pragma unroll
            for (int reg = 0; reg < 4; reg++)
                t_l[quad * 4 + reg][h] = bfr(ct[reg]);
        }
    }

    // qr = q @ rel_emb^T: only needs aQ, so it lives here (rel_emb load
    // latency hides under the t MFMAs above). rows >= 99 are zero.
    if (w < 7) {
        f4 cr = z;
        int rrow = w * 16 + n15;
        bool valid = rrow < 99;
        const float* rp = rel_emb + (valid ? rrow : 0) * 256 + quad * 8;
#pragma unroll
        for (int kk = 0; kk < 8; kk++) {
            const float4* rpp = (const float4*)(rp + kk * 32);
            float4 x0 = rpp[0], x1 = rpp[1];
            if (!valid) { x0 = make_float4(0.f, 0.f, 0.f, 0.f); x1 = x0; }
            cr = __builtin_amdgcn_mfma_f32_16x16x32_bf16(aQ[kk], pack8(x0, x1), cr, 0, 0, 0);
        }
#pragma unroll
        for (int reg = 0; reg < 4; reg++)
            qr_l[quad * 4 + reg][rrow] = cr[reg];  // dup rows get dup values
    }

    // qbk[i] = dot(q[i], bk): wave w (<8) handles row w (4 elems/lane)
    if (w < 8) {
        const short* qp = &q_l[w][lane * 4];
        float4 bkv = *(const float4*)(bk + lane * 4);
        float a0 = bf2f(qp[0]) * bkv.x + bf2f(qp[1]) * bkv.y +
                   bf2f(qp[2]) * bkv.z + bf2f(qp[3]) * bkv.w;
#pragma unroll
        for (int d = 1; d <= 32; d <<= 1) a0 += __shfl_xor(a0, d, 64);
        if (lane == 0) qbk_l[w] = a0;
    }

    // ---- keys nt=0 prefetch: issued pre-barrier so the loads are in flight
    // while the whole block drains the barrier (wkfr dead -> VGPR fits) ----
    float4 kf0[8][2];
    {
        int krow = b * 512 + j0 + n15;   // nt = 0
        const float* kr = keys + krow * 256 + quad * 8;
#pragma unroll
        for (int kk = 0; kk < 8; kk++) {
            const float4* kp = (const float4*)(kr + kk * 32);
            kf0[kk][0] = kp[0];
            kf0[kk][1] = kp[1];
        }
    }
    __syncthreads();

    // ---- Phase C: qk = t @ keys^T, softmax ----
    bf8 aT[8];
#pragma unroll
    for (int kk = 0; kk < 8; kk++)
        aT[kk] = *(const bf8*)&t_l[n15 & 7][kk * 32 + quad * 8];

    f4 c[2] = {z, z};
#pragma unroll
    for (int kk = 0; kk < 8; kk++)
        c[0] = __builtin_amdgcn_mfma_f32_16x16x32_bf16(aT[kk], pack8(kf0[kk][0], kf0[kk][1]),
                                                       c[0], 0, 0, 0);
    {
        int krow = b * 512 + j0 + 16 + n15;  // nt = 1, loads hide under nt=0 MFMAs
        const float* kr = keys + krow * 256 + quad * 8;
#pragma unroll
        for (int kk = 0; kk < 8; kk++) {
            const float4* kp = (const float4*)(kr + kk * 32);
            c[1] = __builtin_amdgcn_mfma_f32_16x16x32_bf16(aT[kk], pack8(kp[0], kp[1]),
                                                           c[1], 0, 0, 0);
        }
    }

    const float scale = 0.0625f;  // 1/sqrt(256)
    float lg[2][4];
#pragma unroll
    for (int nt = 0; nt < 2; nt++)
#pragma unroll
        for (int reg = 0; reg < 4; reg++)
            lg[nt][reg] = (c[nt][reg] + qr_l[quad * 4 + reg][rv[nt][reg]] +
                           qbk_l[(quad & 1) * 4 + reg]) * scale;

    float pm[4];
#pragma unroll
    for (int reg = 0; reg < 4; reg++) {
        float m = fmaxf(lg[0][reg], lg[1][reg]);
#pragma unroll
        for (int d = 1; d <= 8; d <<= 1) m = fmaxf(m, __shfl_xor(m, d, 64));
        pm[reg] = m;
    }
    if (n15 == 0)
#pragma unroll
        for (int reg = 0; reg < 4; reg++) red_m[quad * 4 + reg][w] = pm[reg];
    __syncthreads();
    float M[4];
#pragma unroll
    for (int reg = 0; reg < 4; reg++) {
        f4 a0 = *(const f4*)&red_m[quad * 4 + reg][0];
        f4 a1 = *(const f4*)&red_m[quad * 4 + reg][4];
        f4 a2 = *(const f4*)&red_m[quad * 4 + reg][8];
        f4 a3 = *(const f4*)&red_m[quad * 4 + reg][12];
        float m0 = fmaxf(fmaxf(a0[0], a0[1]), fmaxf(a0[2], a0[3]));
        float m1 = fmaxf(fmaxf(a1[0], a1[1]), fmaxf(a1[2], a1[3]));
        float m2 = fmaxf(fmaxf(a2[0], a2[1]), fmaxf(a2[2], a2[3]));
        float m3 = fmaxf(fmaxf(a3[0], a3[1]), fmaxf(a3[2], a3[3]));
        M[reg] = fmaxf(fmaxf(m0, m1), fmaxf(m2, m3));
    }

    float ps[4];
#pragma unroll
    for (int reg = 0; reg < 4; reg++) {
        float s = 0.f;
#pragma unroll
        for (int nt = 0; nt < 2; nt++) {
            float e = __expf(lg[nt][reg] - M[reg]);
            lg[nt][reg] = e;
            s += e;
        }
#pragma unroll
        for (int d = 1; d <= 8; d <<= 1) s += __shfl_xor(s, d, 64);
        ps[reg] = s;
    }
    if (n15 == 0)
#pragma unroll
        for (int reg = 0; reg < 4; reg++) red_s[quad * 4 + reg][w] = ps[reg];
    __syncthreads();
    float inv[4];
#pragma unroll
    for (int reg = 0; reg < 4; reg++) {
        f4 a0 = *(const f4*)&red_s[quad * 4 + reg][0];
        f4 a1 = *(const f4*)&red_s[quad * 4 + reg][4];
        f4 a2 = *(const f4*)&red_s[quad * 4 + reg][8];
        f4 a3 = *(const f4*)&red_s[quad * 4 + reg][12];
        inv[reg] = 1.f / (a0[0] + a0[1] + a0[2] + a0[3] + a1[0] + a1[1] + a1[2] + a1[3] +
                          a2[0] + a2[1] + a2[2] + a2[3] + a3[0] + a3[1] + a3[2] + a3[3]);
    }

    if (quad < 2) {  // rows 0..7 real; quads 2,3 are duplicates
        float* ob = out + (gi0 + quad * 4) * 512 + j0 + n15;
#pragma unroll
        for (int reg = 0; reg < 4; reg++)
#pragma unroll
            for (int nt = 0; nt < 2; nt++)
                ob[reg * 512 + nt * 16] = lg[nt][reg] * inv[reg];
    }
}

extern "C" void kernel_launch(void* const* d_in, const int* in_sizes, int n_in,
                              void* d_out, int out_size, void* d_ws, size_t ws_size,
                              hipStream_t stream) {
    const float* queries = (const float*)d_in[0];
    const float* keys = (const float*)d_in[1];
    const int* relations = (const int*)d_in[2];
    const float* Wq = (const float*)d_in[3];
    const float* bq = (const float*)d_in[4];
    const float* Wk = (const float*)d_in[5];
    const float* bk = (const float*)d_in[6];
    const float* rel_emb = (const float*)d_in[7];
    float* out = (float*)d_out;

    hipLaunchKernelGGL(fused_attn, dim3(256), dim3(1024), 0, stream,
                       queries, keys, relations, Wq, bq, Wk, bk, rel_emb, out);
}

// Round 7
// 98.701 us; speedup vs baseline: 1.1436x; 1.1282x over previous
//
#include <hip/hip_runtime.h>

typedef __attribute__((ext_vector_type(8))) short bf8;
typedef __attribute__((ext_vector_type(4))) float f4;

// ws layout (short-element offsets)
#define QBF  0         // q  bf16 [2048][256]
#define KBF  524288    // k  bf16 [2048][256]
#define REBF 1048576   // rel_emb bf16 [112][256], rows 99..111 zero

static __device__ __forceinline__ short bfr(float x) {
    union { float f; unsigned u; } v; v.f = x;
    return (short)((v.u + 0x7FFF + ((v.u >> 16) & 1)) >> 16);  // RNE
}
static __device__ __forceinline__ bf8 pack8(float4 a, float4 b) {
    bf8 r;
    r[0] = bfr(a.x); r[1] = bfr(a.y); r[2] = bfr(a.z); r[3] = bfr(a.w);
    r[4] = bfr(b.x); r[5] = bfr(b.y); r[6] = bfr(b.z); r[7] = bfr(b.w);
    return r;
}

// K1: barrier-free projection. out[row][col] = sum_h x[row][h]*W[col][h] + b[col].
// Key insight: the B-fragment for output col n is a CONTIGUOUS slice of W row n
// (x @ W.T needs no transpose) -> load straight from global (L2-resident 256KB),
// no LDS staging, no __syncthreads. Blocks 0..511: 32x64 tiles, 4 waves, each
// wave a 16x32 sub-tile = an independent load->pack->MFMA->store stream
// (2 blocks/CU, 8 waves/CU, free overlap). Blocks 512..518: rel_emb cast.
// R0's LDS version ran ~19us (1 wave/SIMD + barrier-serialized staging).
__global__ __launch_bounds__(256) void proj_kernel(const float* __restrict__ queries,
                                                   const float* __restrict__ keys,
                                                   const float* __restrict__ bq,
                                                   const float* __restrict__ bk,
                                                   const float* __restrict__ Wq,
                                                   const float* __restrict__ Wk,
                                                   const float* __restrict__ rel_emb,
                                                   short* __restrict__ ws) {
    int blk = blockIdx.x;
    int tid = threadIdx.x;

    if (blk >= 512) {
        // rel_emb cast: 7 blocks x 256 thr x 16 shorts = 28672 = 112*256
        int idx = ((blk - 512) * 256 + tid) * 16;
        float4 a = make_float4(0.f, 0.f, 0.f, 0.f), b = a, c = a, d = a;
        if ((idx >> 8) < 99) {
            const float4* s = (const float4*)(rel_emb + idx);
            a = s[0]; b = s[1]; c = s[2]; d = s[3];
        }
        *(bf8*)(ws + REBF + idx) = pack8(a, b);
        *(bf8*)(ws + REBF + idx + 8) = pack8(c, d);
        return;
    }

    int mat = blk >> 8;          // 0 = q, 1 = k
    int t = blk & 255;           // 64 m-tiles x 4 n-tiles
    int m0 = (t >> 2) * 32;
    int n0 = (t & 3) * 64;
    const float* x = mat ? keys : queries;
    const float* W = mat ? Wk : Wq;
    const float* bias = mat ? bk : bq;
    short* outp = ws + (mat ? KBF : QBF);

    int w = tid >> 6;
    int lane = tid & 63;
    int n15 = lane & 15, quad = lane >> 4;
    int wr = w & 1, wc = w >> 1;  // wave -> 16-row strip x 32-col strip

    // A-frags: x rows m0 + wr*16 + n15, packed fp32->bf16
    int mrow = m0 + wr * 16 + n15;
    bf8 afr[8];
#pragma unroll
    for (int kk = 0; kk < 8; kk++) {
        const float4* ap = (const float4*)(x + mrow * 256 + kk * 32 + quad * 8);
        afr[kk] = pack8(ap[0], ap[1]);
    }

    f4 z = {0.f, 0.f, 0.f, 0.f};
    f4 c[2] = {z, z};
#pragma unroll
    for (int nt = 0; nt < 2; nt++) {
        int col = n0 + wc * 32 + nt * 16 + n15;
        const float* wp = W + col * 256 + quad * 8;
#pragma unroll
        for (int kk = 0; kk < 8; kk++) {
            const float4* bp = (const float4*)(wp + kk * 32);
            c[nt] = __builtin_amdgcn_mfma_f32_16x16x32_bf16(afr[kk], pack8(bp[0], bp[1]),
                                                            c[nt], 0, 0, 0);
        }
    }

    int mbase = m0 + wr * 16 + quad * 4;
#pragma unroll
    for (int nt = 0; nt < 2; nt++) {
        int col = n0 + wc * 32 + nt * 16 + n15;
        float bv = bias[col];
#pragma unroll
        for (int reg = 0; reg < 4; reg++)
            outp[(mbase + reg) * 256 + col] = bfr(c[nt][reg] + bv);
    }
}

// K2: fused qk + qr + softmax — R0-exact structure (measured best: ~18 us).
// Block = (b, 8-row i-tile): grid 256 x 512 thr. A-rows duplicated (row =
// n15&7) so the 16x16 MFMA tile carries 8 real rows; dup lanes hit identical
// cache lines (L1/L2-absorbed). 3-barrier softmax (measured faster than online
// recombine in prior session). Do NOT shrink the i-tile: 4-row tiles doubled
// K L2 traffic and tripled this kernel (R2: 52 us).
__global__ __launch_bounds__(512) void attn_kernel(const int* __restrict__ relations,
                                                   const short* __restrict__ ws,
                                                   float* __restrict__ out) {
    __shared__ float qr_l[16][112];
    __shared__ float red_m[16][8];
    __shared__ float red_s[16][8];

    int blk = blockIdx.x;
    int b = blk >> 6;
    int i0 = (blk & 63) * 8;
    int gi0 = b * 512 + i0;
    int w = threadIdx.x >> 6;
    int lane = threadIdx.x & 63;
    int n15 = lane & 15, quad = lane >> 4;
    int j0 = w * 64;

    // prefetch relations: C row m=quad*4+reg -> real row (quad&1)*4+reg
    const int* rb = relations + (gi0 + (quad & 1) * 4) * 512 + j0 + n15;
    int rv[4][4];
#pragma unroll
    for (int reg = 0; reg < 4; reg++)
#pragma unroll
        for (int nt = 0; nt < 4; nt++)
            rv[nt][reg] = rb[reg * 512 + nt * 16];

    const short* qbf = ws + QBF;
    const short* kbf = ws + KBF;
    const short* rebf = ws + REBF;

    // A-frags: q row gi0 + (n15&7)  (rows 8..15 duplicate 0..7)
    int arow = gi0 + (n15 & 7);
    bf8 afr[8];
#pragma unroll
    for (int kk = 0; kk < 8; kk++)
        afr[kk] = *(const bf8*)(qbf + arow * 256 + kk * 32 + quad * 8);

    f4 z = {0.f, 0.f, 0.f, 0.f};
    f4 c[4] = {z, z, z, z};
#pragma unroll
    for (int nt = 0; nt < 4; nt++) {
        int krow = b * 512 + j0 + nt * 16 + n15;
        const short* kr = kbf + krow * 256 + quad * 8;
#pragma unroll
        for (int kk = 0; kk < 8; kk++) {
            bf8 bfrag = *(const bf8*)(kr + kk * 32);
            c[nt] = __builtin_amdgcn_mfma_f32_16x16x32_bf16(afr[kk], bfrag, c[nt], 0, 0, 0);
        }
    }

    if (w < 7) {  // qr tile: rel rows w*16..w*16+15 (rebf zero-padded to 112)
        f4 cq = z;
        const short* rr = rebf + (w * 16 + n15) * 256 + quad * 8;
#pragma unroll
        for (int kk = 0; kk < 8; kk++) {
            bf8 bfrag = *(const bf8*)(rr + kk * 32);
            cq = __builtin_amdgcn_mfma_f32_16x16x32_bf16(afr[kk], bfrag, cq, 0, 0, 0);
        }
#pragma unroll
        for (int reg = 0; reg < 4; reg++)
            qr_l[quad * 4 + reg][w * 16 + n15] = cq[reg];  // dup rows get dup values
    }
    __syncthreads();

    const float scale = 0.0625f;  // 1/sqrt(256)
    float lg[4][4];
#pragma unroll
    for (int nt = 0; nt < 4; nt++)
#pragma unroll
        for (int reg = 0; reg < 4; reg++)
            lg[nt][reg] = (c[nt][reg] + qr_l[quad * 4 + reg][rv[nt][reg]]) * scale;

    float pm[4];
#pragma unroll
    for (int reg = 0; reg < 4; reg++) {
        float m = fmaxf(fmaxf(lg[0][reg], lg[1][reg]), fmaxf(lg[2][reg], lg[3][reg]));
#pragma unroll
        for (int d = 1; d <= 8; d <<= 1) m = fmaxf(m, __shfl_xor(m, d, 64));
        pm[reg] = m;
    }
    if (n15 == 0)
#pragma unroll
        for (int reg = 0; reg < 4; reg++) red_m[quad * 4 + reg][w] = pm[reg];
    __syncthreads();
    float M[4];
#pragma unroll
    for (int reg = 0; reg < 4; reg++) {
        f4 a0 = *(const f4*)&red_m[quad * 4 + reg][0];
        f4 a1 = *(const f4*)&red_m[quad * 4 + reg][4];
        M[reg] = fmaxf(fmaxf(fmaxf(a0[0], a0[1]), fmaxf(a0[2], a0[3])),
                       fmaxf(fmaxf(a1[0], a1[1]), fmaxf(a1[2], a1[3])));
    }

    float ps[4];
#pragma unroll
    for (int reg = 0; reg < 4; reg++) {
        float s = 0.f;
#pragma unroll
        for (int nt = 0; nt < 4; nt++) {
            float e = __expf(lg[nt][reg] - M[reg]);
            lg[nt][reg] = e;
            s += e;
        }
#pragma unroll
        for (int d = 1; d <= 8; d <<= 1) s += __shfl_xor(s, d, 64);
        ps[reg] = s;
    }
    if (n15 == 0)
#pragma unroll
        for (int reg = 0; reg < 4; reg++) red_s[quad * 4 + reg][w] = ps[reg];
    __syncthreads();
    float inv[4];
#pragma unroll
    for (int reg = 0; reg < 4; reg++) {
        f4 a0 = *(const f4*)&red_s[quad * 4 + reg][0];
        f4 a1 = *(const f4*)&red_s[quad * 4 + reg][4];
        inv[reg] = 1.f / (a0[0] + a0[1] + a0[2] + a0[3] + a1[0] + a1[1] + a1[2] + a1[3]);
    }

    if (quad < 2) {  // rows 0..7 real; quads 2,3 are duplicates
        float* ob = out + (gi0 + quad * 4) * 512 + j0 + n15;
#pragma unroll
        for (int reg = 0; reg < 4; reg++)
#pragma unroll
            for (int nt = 0; nt < 4; nt++)
                ob[reg * 512 + nt * 16] = lg[nt][reg] * inv[reg];
    }
}

extern "C" void kernel_launch(void* const* d_in, const int* in_sizes, int n_in,
                              void* d_out, int out_size, void* d_ws, size_t ws_size,
                              hipStream_t stream) {
    const float* queries = (const float*)d_in[0];
    const float* keys = (const float*)d_in[1];
    const int* relations = (const int*)d_in[2];
    const float* Wq = (const float*)d_in[3];
    const float* bq = (const float*)d_in[4];
    const float* Wk = (const float*)d_in[5];
    const float* bk = (const float*)d_in[6];
    const float* rel_emb = (const float*)d_in[7];
    short* wss = (short*)d_ws;
    float* out = (float*)d_out;

    hipLaunchKernelGGL(proj_kernel, dim3(519), dim3(256), 0, stream,
                       queries, keys, bq, bk, Wq, Wk, rel_emb, wss);
    hipLaunchKernelGGL(attn_kernel, dim3(256), dim3(512), 0, stream, relations, wss, out);
}

// Round 8
// 95.008 us; speedup vs baseline: 1.1881x; 1.0389x over previous
//
#include <hip/hip_runtime.h>

typedef __attribute__((ext_vector_type(8))) short bf8;
typedef __attribute__((ext_vector_type(4))) float f4;

// ws layout (short-element offsets)
#define QBF  0         // q  bf16 [2048][256]
#define KBF  524288    // k  bf16 [2048][256]
#define REBF 1048576   // rel_emb bf16 [112][256], rows 99..111 zero

static __device__ __forceinline__ short bfr(float x) {
    union { float f; unsigned u; } v; v.f = x;
    return (short)((v.u + 0x7FFF + ((v.u >> 16) & 1)) >> 16);  // RNE
}
static __device__ __forceinline__ bf8 pack8(float4 a, float4 b) {
    bf8 r;
    r[0] = bfr(a.x); r[1] = bfr(a.y); r[2] = bfr(a.z); r[3] = bfr(a.w);
    r[4] = bfr(b.x); r[5] = bfr(b.y); r[6] = bfr(b.z); r[7] = bfr(b.w);
    return r;
}

// K1: R0-exact proj (best measured two-kernel proj). Blocks 0..255: GEMM tiles
// (M=64 x N=64, 4 waves); blocks 256..262: rel_emb fp32->bf16 cast.
// out[row][col] = sum_h x[row][h]*W[col][h] + bias[col].
// (R7's barrier-free variant regressed: B-frag re-pack per MFMA on the
// critical path. LDS stage pays the pack once cooperatively.)
__global__ __launch_bounds__(256) void proj_kernel(const float* __restrict__ queries,
                                                   const float* __restrict__ keys,
                                                   const float* __restrict__ bq,
                                                   const float* __restrict__ bk,
                                                   const float* __restrict__ Wq,
                                                   const float* __restrict__ Wk,
                                                   const float* __restrict__ rel_emb,
                                                   short* __restrict__ ws) {
    __shared__ short w_l[64 * 264];  // bf16 W tile, row stride 264 shorts (16B-aligned)
    int blk = blockIdx.x;
    int tid = threadIdx.x;

    if (blk >= 256) {
        // rel_emb cast: 7 blocks x 256 thr x 16 shorts = 28672 = 112*256
        int idx = ((blk - 256) * 256 + tid) * 16;
        float4 a = make_float4(0.f, 0.f, 0.f, 0.f), b = a, c = a, d = a;
        if ((idx >> 8) < 99) {
            const float4* s = (const float4*)(rel_emb + idx);
            a = s[0]; b = s[1]; c = s[2]; d = s[3];
        }
        *(bf8*)(ws + REBF + idx) = pack8(a, b);
        *(bf8*)(ws + REBF + idx + 8) = pack8(c, d);
        return;
    }

    int mat = blk >> 7;          // 0 = q, 1 = k
    int t = blk & 127;           // 32 m-tiles x 4 n-tiles
    int m0 = (t >> 2) * 64;
    int n0 = (t & 3) * 64;
    const float* x = mat ? keys : queries;
    const float* W = mat ? Wk : Wq;
    const float* bias = mat ? bk : bq;
    short* outp = ws + (mat ? KBF : QBF);

    int w = tid >> 6;
    int lane = tid & 63;
    int n15 = lane & 15, quad = lane >> 4;

    // stage W[n0..n0+64)[0..256) fp32 -> bf16 LDS (coalesced 32B/lane reads)
#pragma unroll
    for (int cc = 0; cc < 8; cc++) {
        int chunk = cc * 256 + tid;          // 2048 chunks of 8 floats
        int row = chunk >> 5, col8 = chunk & 31;
        const float4* s = (const float4*)(W + (n0 + row) * 256 + col8 * 8);
        *(bf8*)&w_l[row * 264 + col8 * 8] = pack8(s[0], s[1]);
    }

    // A-frags: x rows m0 + w*16 + n15, packed fp32->bf16
    int mrow = m0 + w * 16 + n15;
    bf8 afr[8];
#pragma unroll
    for (int kk = 0; kk < 8; kk++) {
        const float4* ap = (const float4*)(x + mrow * 256 + kk * 32 + quad * 8);
        afr[kk] = pack8(ap[0], ap[1]);
    }
    __syncthreads();

    f4 z = {0.f, 0.f, 0.f, 0.f};
    f4 c[4] = {z, z, z, z};
#pragma unroll
    for (int nt = 0; nt < 4; nt++) {
        const short* wr = &w_l[(nt * 16 + n15) * 264 + quad * 8];
#pragma unroll
        for (int kk = 0; kk < 8; kk++) {
            bf8 bfrag = *(const bf8*)(wr + kk * 32);
            c[nt] = __builtin_amdgcn_mfma_f32_16x16x32_bf16(afr[kk], bfrag, c[nt], 0, 0, 0);
        }
    }

    int mbase = m0 + w * 16 + quad * 4;
#pragma unroll
    for (int nt = 0; nt < 4; nt++) {
        int col = n0 + nt * 16 + n15;
        float bv = bias[col];
#pragma unroll
        for (int reg = 0; reg < 4; reg++)
            outp[(mbase + reg) * 256 + col] = bfr(c[nt][reg] + bv);
    }
}

// K2: fused qk + qr + softmax. Block = (b, 8-row i-tile): grid 256 x 1024 thr
// (16 waves = 4 waves/SIMD; the R0 512-thr version ran 2/SIMD — R5 measured
// the same 2x-TLP change worth ~1.2-1.5x on the fused kernel). Each wave now
// covers 32 j-cols (nt=0..1); traffic identical (each K row read once/block).
// A-rows duplicated (row = n15&7) so the 16x16 MFMA tile carries 8 real rows;
// dup lanes hit identical cache lines. 3-barrier softmax (measured faster
// than online recombine). Do NOT shrink the 8-row i-tile (R2: 4x K traffic).
__global__ __launch_bounds__(1024) void attn_kernel(const int* __restrict__ relations,
                                                    const short* __restrict__ ws,
                                                    float* __restrict__ out) {
    __shared__ float qr_l[16][112];
    __shared__ float red_m[16][16];
    __shared__ float red_s[16][16];

    int blk = blockIdx.x;
    int b = blk >> 6;
    int i0 = (blk & 63) * 8;
    int gi0 = b * 512 + i0;
    int w = threadIdx.x >> 6;        // 16 waves
    int lane = threadIdx.x & 63;
    int n15 = lane & 15, quad = lane >> 4;
    int j0 = w * 32;

    // prefetch relations: C row m=quad*4+reg -> real row (quad&1)*4+reg
    const int* rb = relations + (gi0 + (quad & 1) * 4) * 512 + j0 + n15;
    int rv[2][4];
#pragma unroll
    for (int reg = 0; reg < 4; reg++)
#pragma unroll
        for (int nt = 0; nt < 2; nt++)
            rv[nt][reg] = rb[reg * 512 + nt * 16];

    const short* qbf = ws + QBF;
    const short* kbf = ws + KBF;
    const short* rebf = ws + REBF;

    // A-frags: q row gi0 + (n15&7)  (rows 8..15 duplicate 0..7)
    int arow = gi0 + (n15 & 7);
    bf8 afr[8];
#pragma unroll
    for (int kk = 0; kk < 8; kk++)
        afr[kk] = *(const bf8*)(qbf + arow * 256 + kk * 32 + quad * 8);

    f4 z = {0.f, 0.f, 0.f, 0.f};
    f4 c[2] = {z, z};
#pragma unroll
    for (int nt = 0; nt < 2; nt++) {
        int krow = b * 512 + j0 + nt * 16 + n15;
        const short* kr = kbf + krow * 256 + quad * 8;
#pragma unroll
        for (int kk = 0; kk < 8; kk++) {
            bf8 bfrag = *(const bf8*)(kr + kk * 32);
            c[nt] = __builtin_amdgcn_mfma_f32_16x16x32_bf16(afr[kk], bfrag, c[nt], 0, 0, 0);
        }
    }

    if (w < 7) {  // qr tile: rel rows w*16..w*16+15 (rebf zero-padded to 112)
        f4 cq = z;
        const short* rr = rebf + (w * 16 + n15) * 256 + quad * 8;
#pragma unroll
        for (int kk = 0; kk < 8; kk++) {
            bf8 bfrag = *(const bf8*)(rr + kk * 32);
            cq = __builtin_amdgcn_mfma_f32_16x16x32_bf16(afr[kk], bfrag, cq, 0, 0, 0);
        }
#pragma unroll
        for (int reg = 0; reg < 4; reg++)
            qr_l[quad * 4 + reg][w * 16 + n15] = cq[reg];  // dup rows get dup values
    }
    __syncthreads();

    const float scale = 0.0625f;  // 1/sqrt(256)
    float lg[2][4];
#pragma unroll
    for (int nt = 0; nt < 2; nt++)
#pragma unroll
        for (int reg = 0; reg < 4; reg++)
            lg[nt][reg] = (c[nt][reg] + qr_l[quad * 4 + reg][rv[nt][reg]]) * scale;

    float pm[4];
#pragma unroll
    for (int reg = 0; reg < 4; reg++) {
        float m = fmaxf(lg[0][reg], lg[1][reg]);
#pragma unroll
        for (int d = 1; d <= 8; d <<= 1) m = fmaxf(m, __shfl_xor(m, d, 64));
        pm[reg] = m;
    }
    if (n15 == 0)
#pragma unroll
        for (int reg = 0; reg < 4; reg++) red_m[quad * 4 + reg][w] = pm[reg];
    __syncthreads();
    float M[4];
#pragma unroll
    for (int reg = 0; reg < 4; reg++) {
        f4 a0 = *(const f4*)&red_m[quad * 4 + reg][0];
        f4 a1 = *(const f4*)&red_m[quad * 4 + reg][4];
        f4 a2 = *(const f4*)&red_m[quad * 4 + reg][8];
        f4 a3 = *(const f4*)&red_m[quad * 4 + reg][12];
        float m0 = fmaxf(fmaxf(a0[0], a0[1]), fmaxf(a0[2], a0[3]));
        float m1 = fmaxf(fmaxf(a1[0], a1[1]), fmaxf(a1[2], a1[3]));
        float m2 = fmaxf(fmaxf(a2[0], a2[1]), fmaxf(a2[2], a2[3]));
        float m3 = fmaxf(fmaxf(a3[0], a3[1]), fmaxf(a3[2], a3[3]));
        M[reg] = fmaxf(fmaxf(m0, m1), fmaxf(m2, m3));
    }

    float ps[4];
#pragma unroll
    for (int reg = 0; reg < 4; reg++) {
        float s = 0.f;
#pragma unroll
        for (int nt = 0; nt < 2; nt++) {
            float e = __expf(lg[nt][reg] - M[reg]);
            lg[nt][reg] = e;
            s += e;
        }
#pragma unroll
        for (int d = 1; d <= 8; d <<= 1) s += __shfl_xor(s, d, 64);
        ps[reg] = s;
    }
    if (n15 == 0)
#pragma unroll
        for (int reg = 0; reg < 4; reg++) red_s[quad * 4 + reg][w] = ps[reg];
    __syncthreads();
    float inv[4];
#pragma unroll
    for (int reg = 0; reg < 4; reg++) {
        f4 a0 = *(const f4*)&red_s[quad * 4 + reg][0];
        f4 a1 = *(const f4*)&red_s[quad * 4 + reg][4];
        f4 a2 = *(const f4*)&red_s[quad * 4 + reg][8];
        f4 a3 = *(const f4*)&red_s[quad * 4 + reg][12];
        inv[reg] = 1.f / (a0[0] + a0[1] + a0[2] + a0[3] + a1[0] + a1[1] + a1[2] + a1[3] +
                          a2[0] + a2[1] + a2[2] + a2[3] + a3[0] + a3[1] + a3[2] + a3[3]);
    }

    if (quad < 2) {  // rows 0..7 real; quads 2,3 are duplicates
        float* ob = out + (gi0 + quad * 4) * 512 + j0 + n15;
#pragma unroll
        for (int reg = 0; reg < 4; reg++)
#pragma unroll
            for (int nt = 0; nt < 2; nt++)
                ob[reg * 512 + nt * 16] = lg[nt][reg] * inv[reg];
    }
}

extern "C" void kernel_launch(void* const* d_in, const int* in_sizes, int n_in,
                              void* d_out, int out_size, void* d_ws, size_t ws_size,
                              hipStream_t stream) {
    const float* queries = (const float*)d_in[0];
    const float* keys = (const float*)d_in[1];
    const int* relations = (const int*)d_in[2];
    const float* Wq = (const float*)d_in[3];
    const float* bq = (const float*)d_in[4];
    const float* Wk = (const float*)d_in[5];
    const float* bk = (const float*)d_in[6];
    const float* rel_emb = (const float*)d_in[7];
    short* wss = (short*)d_ws;
    float* out = (float*)d_out;

    hipLaunchKernelGGL(proj_kernel, dim3(263), dim3(256), 0, stream,
                       queries, keys, bq, bk, Wq, Wk, rel_emb, wss);
    hipLaunchKernelGGL(attn_kernel, dim3(256), dim3(1024), 0, stream, relations, wss, out);
}